// Round 1
// 475.001 us; speedup vs baseline: 1.1487x; 1.1487x over previous
//
#include <hip/hip_runtime.h>
#include <cstdint>
#include <cstddef>

typedef float v4f __attribute__((ext_vector_type(4)));
typedef int   v4i __attribute__((ext_vector_type(4)));

// Problem constants (from reference): B=4, N=65536, K=16, D=8, OUT=8
namespace {
constexpr int Bn = 4;
constexpr int Nn = 65536;
constexpr int Kn = 16;
constexpr int NK = Nn * Kn;          // 1<<20
constexpr int TOTAL = Bn * NK;       // 1<<22 = 4,194,304
constexpr int QPB = NK / 4;          // quads per batch = 262144 = 1<<18
constexpr float COUNT_F = 4194304.0f;
constexpr float EPS = 1e-6f;
constexpr float SLOPE = 0.2f;
// out0 = (B,16,N,K) then out1 = (B,8,N,K), concatenated flat
constexpr long long OUT0_TOTAL = (long long)Bn * 16 * NK;  // 67,108,864
}

// ws layout (bytes):
//   [0, 416)            : stats  — [0..7]=sum, [8..15]=sumsq, [16..95]=fused W, [96..103]=fused b
//   [1024, 1024+4MB)    : cpad   — coords padded to float4, B*N entries
//   [1024+4MB, +8MB)    : tf     — features transposed to (B,N,8), as 2 float4 per point

// ---------------- prep: zero stats, pad coords, transpose features ----------------
__global__ __launch_bounds__(256) void prep_kernel(
    const float* __restrict__ coords,     // (B,N,3)
    const float* __restrict__ features,   // (B,8,N)
    float* __restrict__ stats,
    v4f* __restrict__ cpad,               // B*N
    v4f* __restrict__ tf)                 // B*N*2
{
    if (blockIdx.x == 0 && threadIdx.x < 16) stats[threadIdx.x] = 0.0f;
    int t = blockIdx.x * blockDim.x + threadIdx.x;   // 0 .. B*N-1
    if (t >= Bn * Nn) return;
    int b = t >> 16;             // N = 65536
    int n = t & (Nn - 1);
    const float* c = coords + (size_t)t * 3;
    v4f cv = {c[0], c[1], c[2], 0.0f};
    cpad[t] = cv;
    const float* fb = features + (size_t)b * 8 * Nn + n;
    v4f lo = {fb[0 * Nn], fb[1 * Nn], fb[2 * Nn], fb[3 * Nn]};
    v4f hi = {fb[4 * Nn], fb[5 * Nn], fb[6 * Nn], fb[7 * Nn]};
    tf[2 * t]     = lo;
    tf[2 * t + 1] = hi;
}

// ---------------- fallback stats init (no-prep path) ----------------
__global__ void init_kernel(float* __restrict__ stats) {
    if (threadIdx.x < 16) stats[threadIdx.x] = 0.0f;
}

// ---------------- pass 1: per-channel sum & sumsq of pre-BN y ----------------
// k-quad per thread; XCD-pinned batch mapping: blocks with (blockIdx&7)>>1 == b
// only touch batch b's 1 MB cpad -> stays resident in that XCD's 4 MB L2.
template <bool PREP>
__global__ __launch_bounds__(256) void reduce_kernel(
    const v4i* __restrict__ nbr4,         // (B,N,K/4) int4
    const v4f* __restrict__ cpad,
    const float* __restrict__ coords,
    const float* __restrict__ conv_w,     // (8,10)
    const float* __restrict__ conv_b,     // (8,)
    float* __restrict__ stats)
{
    float w[80];
    #pragma unroll
    for (int i = 0; i < 80; i++) w[i] = conv_w[i];   // uniform -> SGPR
    float bb[8];
    #pragma unroll
    for (int i = 0; i < 8; i++) bb[i] = conv_b[i];

    float s[8], sq[8];
    #pragma unroll
    for (int i = 0; i < 8; i++) { s[i] = 0.0f; sq[i] = 0.0f; }

    int xcd = blockIdx.x & 7;
    int b   = xcd >> 1;                                  // 2 XCDs per batch
    int wb  = ((blockIdx.x >> 3) << 1) | (xcd & 1);      // 0 .. gridDim/4-1
    int stride = (gridDim.x >> 2) * blockDim.x;          // threads per batch
    const float* cb = coords + (size_t)b * Nn * 3;

    for (int ql = wb * blockDim.x + threadIdx.x; ql < QPB; ql += stride) {
        v4i idx = __builtin_nontemporal_load(&nbr4[(b << 18) + ql]);
        int id[4] = {idx.x, idx.y, idx.z, idx.w};
        int n = ql >> 2;
        float ex, ey, ez;
        if (PREP) {
            v4f e = cpad[(b << 16) + n];
            ex = e.x; ey = e.y; ez = e.z;
        } else {
            ex = cb[n * 3]; ey = cb[n * 3 + 1]; ez = cb[n * 3 + 2];
        }
        #pragma unroll
        for (int k = 0; k < 4; k++) {
            float nx, ny, nz;
            if (PREP) {
                v4f q = cpad[(b << 16) + id[k]];
                nx = q.x; ny = q.y; nz = q.z;
            } else {
                nx = cb[id[k] * 3]; ny = cb[id[k] * 3 + 1]; nz = cb[id[k] * 3 + 2];
            }
            float rx = ex - nx, ry = ey - ny, rz = ez - nz;
            float dist = sqrtf(rx * rx + ry * ry + rz * rz);
            float rf[10] = {dist, rx, ry, rz, ex, ey, ez, nx, ny, nz};
            #pragma unroll
            for (int o = 0; o < 8; o++) {
                float y = bb[o];
                #pragma unroll
                for (int c = 0; c < 10; c++) y = fmaf(w[o * 10 + c], rf[c], y);
                s[o] += y;
                sq[o] = fmaf(y, y, sq[o]);
            }
        }
    }

    // wave-64 butterfly reduction of 16 values
    #pragma unroll
    for (int i = 0; i < 8; i++) {
        #pragma unroll
        for (int off = 32; off > 0; off >>= 1) {
            s[i]  += __shfl_xor(s[i], off, 64);
            sq[i] += __shfl_xor(sq[i], off, 64);
        }
    }
    __shared__ float ls[4][16];
    int lane = threadIdx.x & 63;
    int wv = threadIdx.x >> 6;
    if (lane == 0) {
        #pragma unroll
        for (int i = 0; i < 8; i++) { ls[wv][i] = s[i]; ls[wv][8 + i] = sq[i]; }
    }
    __syncthreads();
    if (threadIdx.x < 16) {
        float a = ls[0][threadIdx.x] + ls[1][threadIdx.x]
                + ls[2][threadIdx.x] + ls[3][threadIdx.x];
        atomicAdd(&stats[threadIdx.x], a);
    }
}

// ---------------- finalize: fold BN into conv weights ----------------
__global__ void finalize_kernel(
    const float* __restrict__ conv_w,
    const float* __restrict__ conv_b,
    const float* __restrict__ gamma,
    const float* __restrict__ beta,
    float* __restrict__ stats)
{
    int j = threadIdx.x;
    if (j >= 88) return;
    int o = (j < 80) ? (j / 10) : (j - 80);
    float mean = stats[o] * (1.0f / COUNT_F);
    float var = stats[8 + o] * (1.0f / COUNT_F) - mean * mean;
    var = fmaxf(var, 0.0f);
    float scale = gamma[o] * rsqrtf(var + EPS);
    if (j < 80) stats[16 + j] = conv_w[j] * scale;                    // fused W
    else        stats[96 + o] = (conv_b[o] - mean) * scale + beta[o]; // fused b
}

// ---------------- pass 2: recompute y (fused BN), gather nf, write outputs ----------------
// One k-quad per thread (grid exactly covers B*N*K/4). All 24 output channels
// become float4 nontemporal stores (4x fewer store instructions).
template <bool PREP>
__global__ __launch_bounds__(256) void output_kernel(
    const v4i* __restrict__ nbr4,
    const v4f* __restrict__ cpad,
    const float* __restrict__ coords,
    const v4f* __restrict__ tf,           // (B,N,8) as 2x float4
    const float* __restrict__ features,   // raw (B,8,N) for fallback
    const float* __restrict__ stats,
    float* __restrict__ out)
{
    float w[80];
    #pragma unroll
    for (int i = 0; i < 80; i++) w[i] = stats[16 + i];  // uniform -> SGPR
    float bb[8];
    #pragma unroll
    for (int i = 0; i < 8; i++) bb[i] = stats[96 + i];

    int xcd = blockIdx.x & 7;
    int b   = xcd >> 1;                                  // 2 XCDs per batch
    int wb  = ((blockIdx.x >> 3) << 1) | (xcd & 1);      // 0..1023
    int ql  = wb * blockDim.x + threadIdx.x;             // 0..262143 (quad id in batch)
    int n   = ql >> 2;

    v4i idx = __builtin_nontemporal_load(&nbr4[(b << 18) + ql]);
    int id[4] = {idx.x, idx.y, idx.z, idx.w};

    const float* cb = coords + (size_t)b * Nn * 3;
    float ex, ey, ez;
    if (PREP) {
        v4f e = cpad[(b << 16) + n];
        ex = e.x; ey = e.y; ez = e.z;
    } else {
        ex = cb[n * 3]; ey = cb[n * 3 + 1]; ez = cb[n * 3 + 2];
    }

    float* o0 = out + ((size_t)b << 24) + (size_t)ql * 4;           // b*16*NK + r
    float* o1 = out + OUT0_TOTAL + ((size_t)(b * 8) << 20) + (size_t)ql * 4;

    // ---- neighbour feature gather -> out0 channels 0..7 (float4 stores) ----
    if (PREP) {
        v4f lo[4], hi[4];
        #pragma unroll
        for (int k = 0; k < 4; k++) {
            lo[k] = tf[2 * ((b << 16) + id[k])];
            hi[k] = tf[2 * ((b << 16) + id[k]) + 1];
        }
        #pragma unroll
        for (int c = 0; c < 4; c++) {
            v4f vlo = {lo[0][c], lo[1][c], lo[2][c], lo[3][c]};
            v4f vhi = {hi[0][c], hi[1][c], hi[2][c], hi[3][c]};
            __builtin_nontemporal_store(vlo, (v4f*)(o0 + (size_t)c * NK));
            __builtin_nontemporal_store(vhi, (v4f*)(o0 + (size_t)(4 + c) * NK));
        }
    } else {
        const float* fb = features + (size_t)b * 8 * Nn;
        #pragma unroll
        for (int d = 0; d < 8; d++) {
            v4f v = {fb[(size_t)d * Nn + id[0]], fb[(size_t)d * Nn + id[1]],
                     fb[(size_t)d * Nn + id[2]], fb[(size_t)d * Nn + id[3]]};
            __builtin_nontemporal_store(v, (v4f*)(o0 + (size_t)d * NK));
        }
    }

    // ---- y channels -> out0 channels 8..15 and out1 (float4 stores) ----
    float acc[8][4];
    #pragma unroll
    for (int k = 0; k < 4; k++) {
        float nx, ny, nz;
        if (PREP) {
            v4f q = cpad[(b << 16) + id[k]];
            nx = q.x; ny = q.y; nz = q.z;
        } else {
            nx = cb[id[k] * 3]; ny = cb[id[k] * 3 + 1]; nz = cb[id[k] * 3 + 2];
        }
        float rx = ex - nx, ry = ey - ny, rz = ez - nz;
        float dist = sqrtf(rx * rx + ry * ry + rz * rz);
        float rf[10] = {dist, rx, ry, rz, ex, ey, ez, nx, ny, nz};
        #pragma unroll
        for (int o = 0; o < 8; o++) {
            float y = bb[o];
            #pragma unroll
            for (int c = 0; c < 10; c++) y = fmaf(w[o * 10 + c], rf[c], y);
            acc[o][k] = fmaxf(y, SLOPE * y);   // LeakyReLU(0.2)
        }
    }
    #pragma unroll
    for (int o = 0; o < 8; o++) {
        v4f v = {acc[o][0], acc[o][1], acc[o][2], acc[o][3]};
        __builtin_nontemporal_store(v, (v4f*)(o0 + (size_t)(8 + o) * NK));
        __builtin_nontemporal_store(v, (v4f*)(o1 + (size_t)o * NK));
    }
}

extern "C" void kernel_launch(void* const* d_in, const int* in_sizes, int n_in,
                              void* d_out, int out_size, void* d_ws, size_t ws_size,
                              hipStream_t stream) {
    const float* coords   = (const float*)d_in[0];   // (4,65536,3)
    const float* features = (const float*)d_in[1];   // (4,8,65536,1)
    const int*   nbr      = (const int*)d_in[2];     // (4,65536,16)
    const float* conv_w   = (const float*)d_in[3];   // (8,10)
    const float* conv_b   = (const float*)d_in[4];   // (8,)
    const float* gamma    = (const float*)d_in[5];   // (8,)
    const float* beta     = (const float*)d_in[6];   // (8,)
    float* out = (float*)d_out;
    const v4i* nbr4 = (const v4i*)nbr;

    float* stats = (float*)d_ws;
    const size_t CPAD_OFF = 1024;
    const size_t CPAD_BYTES = (size_t)Bn * Nn * 4 * sizeof(float);   // 4 MB
    const size_t TF_OFF = CPAD_OFF + CPAD_BYTES;
    const size_t TF_BYTES = (size_t)Bn * Nn * 8 * sizeof(float);     // 8 MB
    const size_t NEED = TF_OFF + TF_BYTES;
    v4f* cpad = (v4f*)((char*)d_ws + CPAD_OFF);
    v4f* tf   = (v4f*)((char*)d_ws + TF_OFF);

    const bool prep = (ws_size >= NEED);
    if (prep) {
        prep_kernel<<<(Bn * Nn) / 256, 256, 0, stream>>>(coords, features, stats, cpad, tf);
        reduce_kernel<true><<<1024, 256, 0, stream>>>(nbr4, cpad, coords, conv_w, conv_b, stats);
    } else {
        init_kernel<<<1, 64, 0, stream>>>(stats);
        reduce_kernel<false><<<1024, 256, 0, stream>>>(nbr4, cpad, coords, conv_w, conv_b, stats);
    }
    finalize_kernel<<<1, 128, 0, stream>>>(conv_w, conv_b, gamma, beta, stats);
    if (prep)
        output_kernel<true><<<4096, 256, 0, stream>>>(nbr4, cpad, coords, tf, features, stats, out);
    else
        output_kernel<false><<<4096, 256, 0, stream>>>(nbr4, cpad, coords, tf, features, stats, out);
}